// Round 14
// baseline (208.412 us; speedup 1.0000x reference)
//
#include <hip/hip_runtime.h>

#define B_  4
#define L_  4096
#define D_  2048
#define HD_ 128
#define M_  (B_*L_)   // 16384

typedef __attribute__((ext_vector_type(8))) short short8;
typedef __attribute__((ext_vector_type(4))) float f32x4;
typedef __attribute__((ext_vector_type(16))) float f32x16;
typedef __attribute__((ext_vector_type(4))) unsigned short u16x4;
typedef __attribute__((ext_vector_type(4))) unsigned int u32x4;
typedef unsigned short u16;

__device__ __forceinline__ u16 f2bf(float f){
  union { float f; unsigned u; } v; v.f = f;
  unsigned r = v.u + 0x7FFFu + ((v.u >> 16) & 1u);
  return (u16)(r >> 16);
}

__device__ __forceinline__ unsigned cvtpk_bf16(float a, float b){
  unsigned r;
  asm volatile("v_cvt_pk_bf16_f32 %0, %1, %2" : "=v"(r) : "v"(a), "v"(b));
  return r;
}

// ---------------- prep_w: weights -> bf16 fragment-major -------------------
// Wf_qkv (32x32 B-frag chunks): chunk = (K>>4)*12 + (C>>5);
//   lane = ((K>>3)&1)*32 + (C&31), j = K&7.
// Wf_o (16x16 chunks for proj): chunk = (K>>5)*128 + (C>>4);
//   lane = ((K>>3)&3)*16 + (C&15), j = K&7.
__global__ __launch_bounds__(256) void prepw_kernel(
    const float* __restrict__ Wq, const float* __restrict__ Wk,
    const float* __restrict__ Wv, const float* __restrict__ Wo,
    u16* __restrict__ Wf_qkv, u16* __restrict__ Wf_o)
{
  __shared__ float T[64][68];
  const int tid = threadIdx.x;
  int tb = blockIdx.x;                 // 0..255
  int mat = tb >> 6, tt = tb & 63;
  const float* src; int Cw, rt, ct;
  if (mat < 3) {
    src = (mat==0) ? Wq : (mat==1) ? Wk : Wv;
    Cw = HD_; rt = tt >> 1; ct = tt & 1;
  } else {
    src = Wo;
    Cw = D_; rt = tt >> 5; ct = tt & 31;
  }
  int r0 = rt*64, c0 = ct*64;
  #pragma unroll
  for (int i=0;i<4;i++){
    int fid = i*256 + tid;
    int row = fid >> 4, c4 = (fid & 15) * 4;
    float4 v = *reinterpret_cast<const float4*>(src + (size_t)(r0+row)*Cw + c0 + c4);
    *reinterpret_cast<float4*>(&T[row][c4]) = v;
  }
  __syncthreads();
  #pragma unroll
  for (int i=0;i<2;i++){
    int sid = i*256 + tid;
    int crow = sid >> 3, k8 = (sid & 7) * 8;
    short8 o;
    #pragma unroll
    for (int j=0;j<8;j++) o[j] = (short)f2bf(T[k8+j][crow]);
    int K = r0 + k8;
    if (mat < 3) {
      int C = mat*128 + c0 + crow;           // global col 0..383
      size_t off = ((size_t)(K>>4)*12 + (C>>5))*512
                 + ((((K>>3)&1))*32 + (C&31))*8;
      *reinterpret_cast<short8*>(Wf_qkv + off) = o;
    } else {
      int C = c0 + crow;                     // global col 0..2047
      size_t off = ((size_t)(K>>5)*128 + (C>>4))*512
                 + ((((K>>3)&3))*16 + (C&15))*8;
      *reinterpret_cast<short8*>(Wf_o + off) = o;
    }
  }
}

// ---------------- fused QKV GEMM: direct-x, barrier-less, deep-pipelined ---
// grid 256 (BM=64), 512 thr = 8 waves (wr=w>>2 x wc=w&3), wave = 32x96.
// A: x fp32 direct (lane-pair covers 64B/row -> 32 full lines/instr-pair),
// cvt_pk in-reg. B: frag-major 1KB chunks from L2. Group-of-4 double-buffer
// register pipeline, zero barriers, zero LDS.
__global__ __launch_bounds__(512, 2) void qkv_kernel(
    const float* __restrict__ x, const u16* __restrict__ Wf,
    const float* __restrict__ bq, const float* __restrict__ bk,
    const float* __restrict__ bv,
    u16* __restrict__ Q, u16* __restrict__ Kf, u16* __restrict__ Vf)
{
  const int rb = blockIdx.x;          // 0..255
  const int tid = threadIdx.x;
  const int lane = tid & 63, w = tid >> 6;
  const int wr = w >> 2, wc = w & 3;
  const int l31 = lane & 31, hi = lane >> 5;

  const float* aP = x + (size_t)(rb*64 + wr*32 + l31)*D_ + hi*8;
  const u16*   bP = Wf + (size_t)(wc*3)*512 + lane*8;

  f32x16 acc[3];
  #pragma unroll
  for (int nb=0;nb<3;nb++)
    #pragma unroll
    for (int i=0;i<16;i++) acc[nb][i] = 0.f;

  float4 a0A[4], a1A[4], a0B[4], a1B[4];
  short8 gbA[4][3], gbB[4][3];

  // prologue: group 0 -> buffer A
  #pragma unroll
  for (int s=0;s<4;s++){
    a0A[s] = *reinterpret_cast<const float4*>(aP + (size_t)s*16);
    a1A[s] = *reinterpret_cast<const float4*>(aP + (size_t)s*16 + 4);
    #pragma unroll
    for (int n=0;n<3;n++)
      gbA[s][n] = *reinterpret_cast<const short8*>(bP + ((size_t)s*12 + n)*512);
  }

  #pragma unroll 1
  for (int g = 0; g < 32; g += 2) {
    // load group g+1 -> B buffers
    if (g + 1 < 32) {
      const float* ap = aP + (size_t)(g+1)*4*16;
      const u16*   bp = bP + (size_t)(g+1)*48*512;
      #pragma unroll
      for (int s=0;s<4;s++){
        a0B[s] = *reinterpret_cast<const float4*>(ap + (size_t)s*16);
        a1B[s] = *reinterpret_cast<const float4*>(ap + (size_t)s*16 + 4);
        #pragma unroll
        for (int n=0;n<3;n++)
          gbB[s][n] = *reinterpret_cast<const short8*>(bp + ((size_t)s*12 + n)*512);
      }
    }
    // compute group g (buffer A)
    __builtin_amdgcn_s_setprio(1);
    #pragma unroll
    for (int s=0;s<4;s++){
      union { u32x4 u; short8 s8; } fa;
      fa.u[0] = cvtpk_bf16(a0A[s].x, a0A[s].y);
      fa.u[1] = cvtpk_bf16(a0A[s].z, a0A[s].w);
      fa.u[2] = cvtpk_bf16(a1A[s].x, a1A[s].y);
      fa.u[3] = cvtpk_bf16(a1A[s].z, a1A[s].w);
      #pragma unroll
      for (int n=0;n<3;n++)
        acc[n] = __builtin_amdgcn_mfma_f32_32x32x16_bf16(fa.s8, gbA[s][n], acc[n], 0, 0, 0);
    }
    __builtin_amdgcn_s_setprio(0);
    // load group g+2 -> A buffers
    if (g + 2 < 32) {
      const float* ap = aP + (size_t)(g+2)*4*16;
      const u16*   bp = bP + (size_t)(g+2)*48*512;
      #pragma unroll
      for (int s=0;s<4;s++){
        a0A[s] = *reinterpret_cast<const float4*>(ap + (size_t)s*16);
        a1A[s] = *reinterpret_cast<const float4*>(ap + (size_t)s*16 + 4);
        #pragma unroll
        for (int n=0;n<3;n++)
          gbA[s][n] = *reinterpret_cast<const short8*>(bp + ((size_t)s*12 + n)*512);
      }
    }
    // compute group g+1 (buffer B)
    __builtin_amdgcn_s_setprio(1);
    #pragma unroll
    for (int s=0;s<4;s++){
      union { u32x4 u; short8 s8; } fa;
      fa.u[0] = cvtpk_bf16(a0B[s].x, a0B[s].y);
      fa.u[1] = cvtpk_bf16(a0B[s].z, a0B[s].w);
      fa.u[2] = cvtpk_bf16(a1B[s].x, a1B[s].y);
      fa.u[3] = cvtpk_bf16(a1B[s].z, a1B[s].w);
      #pragma unroll
      for (int n=0;n<3;n++)
        acc[n] = __builtin_amdgcn_mfma_f32_32x32x16_bf16(fa.s8, gbB[s][n], acc[n], 0, 0, 0);
    }
    __builtin_amdgcn_s_setprio(0);
  }

  // epilogue: C cell col = l31, row_local = 4*hi + (r&3) + 8*(r>>2)
  const float qscale = 0.08838834764831845f;  // 1/sqrt(128)
  const int bb = rb >> 6;
  const int kt = rb & 63;
  const size_t kvBase = ((size_t)bb*64 + kt)*16;
  #pragma unroll
  for (int nb=0; nb<3; nb++){
    const int colbase = wc*96 + nb*32;
    const int j = colbase >> 7;               // 0:Q 1:K 2:V, uniform
    const int col = colbase + l31;
    const int c = col & 127;
    const float bi = (j==0) ? bq[c] : (j==1) ? bk[c] : bv[c];
    if (j == 0) {
      #pragma unroll
      for (int r=0;r<16;r++){
        int row = rb*64 + wr*32 + 4*hi + (r&3) + 8*(r>>2);
        Q[(size_t)row*HD_ + c] = f2bf((acc[nb][r] + bi) * qscale);
      }
    } else if (j == 1) {
      int ksd = c >> 4, hid = (c >> 3) & 1, jd = c & 7;
      #pragma unroll
      for (int r=0;r<16;r++){
        int l31k = 8*(r>>2) + 4*hi + (r&3);
        Kf[(kvBase + wr*8 + ksd)*512 + (hid*32 + l31k)*8 + jd]
            = f2bf(acc[nb][r] + bi);
      }
    } else {
      int nbv = c >> 5;
      #pragma unroll
      for (int g2=0; g2<4; g2++){
        int ksv = wr*2 + (g2>>1), hiv = g2&1, j0 = 4*hi;
        u16x4 v4;
        #pragma unroll
        for (int q=0;q<4;q++) v4[q] = f2bf(acc[nb][4*g2+q] + bi);
        *reinterpret_cast<u16x4*>(
            Vf + (kvBase + ksv*4 + nbv)*512 + (hiv*32 + l31)*8 + j0) = v4;
      }
    }
  }
}

// ---------------- flash attention: 32x32 swapped-QK^T, frag-major K/V ------
__global__ __launch_bounds__(256, 2) void attn_kernel(
    const u16* __restrict__ Qg, const u16* __restrict__ Kfg,
    const u16* __restrict__ Vfg, u16* __restrict__ AOf)
{
  const int blk = blockIdx.x;
  const int xcd = blk & 7;
  const int sub = blk >> 3;                    // 0..63
  const int b   = xcd >> 1;                    // batch -> XCD pair
  const int strip = 127 - (2*sub + (xcd & 1)); // long strips dispatch first
  const int q0  = strip * 32;
  const int KT  = (strip >> 1) + 1;            // #64-key tiles

  const int tid = threadIdx.x, lane = tid & 63, w = tid >> 6;
  const int l31 = lane & 31;
  const int hi  = lane >> 5;

  const u16* Qb  = Qg  + (size_t)b * L_ * HD_;
  const u16* Kfb = Kfg + (size_t)b * 64 * 8192 + lane*8;
  const u16* Vfb = Vfg + (size_t)b * 64 * 8192 + lane*8;

  __shared__ __attribute__((aligned(16))) float Ol[4][32][132];
  __shared__ float Ml[4][32], Ll[4][32];

  short8 qf[8];
  #pragma unroll
  for (int ks=0; ks<8; ks++)
    qf[ks] = *reinterpret_cast<const short8*>(
        &Qb[(size_t)(q0 + l31)*HD_ + ks*16 + hi*8]);

  f32x16 O[4];
  #pragma unroll
  for (int nb=0; nb<4; nb++)
    #pragma unroll
    for (int i=0;i<16;i++) O[nb][i] = 0.f;
  float m_ = -__builtin_inff();
  float l_ = 0.f;

  for (int kt = w; kt < KT; kt += 4) {
    const u16* Kt = Kfb + (size_t)kt*8192;
    f32x16 s[2];
    #pragma unroll
    for (int n=0;n<2;n++)
      #pragma unroll
      for (int i=0;i<16;i++) s[n][i] = 0.f;
    __builtin_amdgcn_s_setprio(1);
    #pragma unroll
    for (int ks=0;ks<8;ks++)
      #pragma unroll
      for (int n=0;n<2;n++){
        short8 ka = *reinterpret_cast<const short8*>(Kt + (n*8 + ks)*512);
        s[n] = __builtin_amdgcn_mfma_f32_32x32x16_bf16(ka, qf[ks], s[n], 0, 0, 0);
      }
    __builtin_amdgcn_s_setprio(0);

    if (kt == KT-1) {
      #pragma unroll
      for (int n=0;n<2;n++)
        #pragma unroll
        for (int reg=0;reg<16;reg++){
          int key = kt*64 + n*32 + (reg&3) + 8*(reg>>2) + 4*hi;
          if (key > q0 + l31) s[n][reg] = -__builtin_inff();
        }
    }

    float pmax = s[0][0];
    #pragma unroll
    for (int n=0;n<2;n++)
      #pragma unroll
      for (int reg=0;reg<16;reg++) pmax = fmaxf(pmax, s[n][reg]);
    pmax = fmaxf(pmax, __shfl_xor(pmax, 32, 64));

    if (!__all(pmax <= m_ + 8.f)) {
      float mnew = fmaxf(m_, pmax);
      float alpha = __expf(m_ - mnew);
      m_ = mnew;
      l_ *= alpha;
      #pragma unroll
      for (int nb=0; nb<4; nb++)
        #pragma unroll
        for (int i=0;i<16;i++) O[nb][i] *= alpha;
    }

    float rsum = 0.f;
    #pragma unroll
    for (int n=0;n<2;n++)
      #pragma unroll
      for (int reg=0;reg<16;reg++){
        float p = __expf(s[n][reg] - m_);
        s[n][reg] = p;
        rsum += p;
      }
    rsum += __shfl_xor(rsum, 32, 64);
    l_ += rsum;

    unsigned c[2][8], ox[2][8];
    #pragma unroll
    for (int n=0;n<2;n++)
      #pragma unroll
      for (int i=0;i<8;i++)
        c[n][i] = cvtpk_bf16(s[n][2*i], s[n][2*i+1]);
    #pragma unroll
    for (int n=0;n<2;n++)
      #pragma unroll
      for (int i=0;i<8;i++)
        ox[n][i] = (unsigned)__shfl_xor((int)c[n][i], 32, 64);

    short8 pb[4];
    #pragma unroll
    for (int n=0;n<2;n++)
      #pragma unroll
      for (int sB=0;sB<2;sB++){
        union { u32x4 u; short8 s8; } t;
        t.u[0] = hi ? ox[n][4*sB+2] : c[n][4*sB+0];
        t.u[1] = hi ? ox[n][4*sB+3] : c[n][4*sB+1];
        t.u[2] = hi ? c[n][4*sB+2]  : ox[n][4*sB+0];
        t.u[3] = hi ? c[n][4*sB+3]  : ox[n][4*sB+1];
        pb[2*n+sB] = t.s8;
      }

    const u16* Vt2 = Vfb + (size_t)kt*8192;
    __builtin_amdgcn_s_setprio(1);
    #pragma unroll
    for (int ks=0; ks<4; ks++){
      #pragma unroll
      for (int nb=0; nb<4; nb++){
        short8 av = *reinterpret_cast<const short8*>(Vt2 + (ks*4 + nb)*512);
        O[nb] = __builtin_amdgcn_mfma_f32_32x32x16_bf16(av, pb[ks], O[nb], 0, 0, 0);
      }
    }
    __builtin_amdgcn_s_setprio(0);
  }

  if (hi == 0) { Ml[w][l31] = m_; Ll[w][l31] = l_; }
  #pragma unroll
  for (int nb=0; nb<4; nb++)
    #pragma unroll
    for (int g=0; g<4; g++){
      f32x4 v;
      v[0]=O[nb][4*g+0]; v[1]=O[nb][4*g+1]; v[2]=O[nb][4*g+2]; v[3]=O[nb][4*g+3];
      *reinterpret_cast<f32x4*>(&Ol[w][l31][nb*32 + g*8 + hi*4]) = v;
    }
  __syncthreads();

  {
    int q  = tid >> 3;
    int dc = (tid & 7) * 16;
    float mw[4], lw[4];
    float M = -__builtin_inff();
    #pragma unroll
    for (int w2=0; w2<4; w2++){ mw[w2]=Ml[w2][q]; lw[w2]=Ll[w2][q]; M = fmaxf(M, mw[w2]); }
    float den = 0.f, cw[4];
    #pragma unroll
    for (int w2=0; w2<4; w2++){ float e = __expf(mw[w2]-M); cw[w2]=e; den += lw[w2]*e; }
    float inv = 1.0f/den;
    float o[16];
    #pragma unroll
    for (int j=0;j<16;j++) o[j] = 0.f;
    #pragma unroll
    for (int w2=0; w2<4; w2++){
      #pragma unroll
      for (int g=0; g<4; g++){
        f32x4 p = *reinterpret_cast<const f32x4*>(&Ol[w2][q][dc + g*4]);
        #pragma unroll
        for (int j=0;j<4;j++) o[g*4+j] += cw[w2]*p[j];
      }
    }
    short8 st0, st1;
    #pragma unroll
    for (int j=0;j<8;j++){ st0[j] = (short)f2bf(o[j]*inv); st1[j] = (short)f2bf(o[8+j]*inv); }
    size_t rowg = (size_t)b*L_ + q0 + q;
    size_t rb2g = rowg >> 5;
    int qq = (int)(rowg & 31);
    int mA = qq >> 4, l15A = qq & 15;
    int ks0 = dc >> 5,      lh0 = (dc >> 3) & 3;
    int ks1 = (dc+8) >> 5,  lh1 = ((dc+8) >> 3) & 3;
    *reinterpret_cast<short8*>(AOf + ((rb2g*4 + ks0)*2 + mA)*512 + (lh0*16 + l15A)*8) = st0;
    *reinterpret_cast<short8*>(AOf + ((rb2g*4 + ks1)*2 + mA)*512 + (lh1*16 + l15A)*8) = st1;
  }
}

// ---------------- output projection: frag-major, LDS-free, single pass -----
__global__ __launch_bounds__(256) void proj_kernel(
    const u16* __restrict__ AOf, const u16* __restrict__ Wf_o,
    const float* __restrict__ bo, float* __restrict__ out)
{
  const int nb  = blockIdx.x;   // 0..7
  const int rbk = blockIdx.y;   // 0..511
  const int tid = threadIdx.x, lane = tid & 63, w = tid >> 6;
  const int l15 = lane & 15, lhi = lane >> 4;

  const u16* faBase = AOf  + (size_t)rbk*8*512 + lane*8;
  const u16* fbBase = Wf_o + lane*8;

  f32x4 acc[2][4];
  f32x4 zero4 = {0.f,0.f,0.f,0.f};
  #pragma unroll
  for (int m=0;m<2;m++)
    #pragma unroll
    for (int n=0;n<4;n++) acc[m][n] = zero4;

  #pragma unroll
  for (int ks=0; ks<4; ks++){
    short8 fa[2], fb[4];
    #pragma unroll
    for (int m=0;m<2;m++)
      fa[m] = *reinterpret_cast<const short8*>(faBase + (ks*2 + m)*512);
    #pragma unroll
    for (int n=0;n<4;n++)
      fb[n] = *reinterpret_cast<const short8*>(
          fbBase + (size_t)(ks*128 + nb*16 + w*4 + n)*512);
    #pragma unroll
    for (int m=0;m<2;m++)
      #pragma unroll
      for (int n=0;n<4;n++)
        acc[m][n] = __builtin_amdgcn_mfma_f32_16x16x32_bf16(fa[m], fb[n], acc[m][n], 0, 0, 0);
  }

  #pragma unroll
  for (int n=0;n<4;n++){
    int col = nb*256 + w*64 + n*16 + l15;
    float bi = bo[col];
    #pragma unroll
    for (int m=0;m<2;m++){
      int row = rbk*32 + m*16 + (lhi<<2);
      #pragma unroll
      for (int r=0;r<4;r++)
        out[(size_t)(row+r)*D_ + col] = acc[m][n][r] + bi;
    }
  }
}

// ---------------- launch ----------------
extern "C" void kernel_launch(void* const* d_in, const int* in_sizes, int n_in,
                              void* d_out, int out_size, void* d_ws, size_t ws_size,
                              hipStream_t stream) {
  const float* x  = (const float*)d_in[0];
  const float* Wq = (const float*)d_in[1];
  const float* bq = (const float*)d_in[2];
  const float* Wk = (const float*)d_in[3];
  const float* bk = (const float*)d_in[4];
  const float* Wv = (const float*)d_in[5];
  const float* bv = (const float*)d_in[6];
  const float* Wo = (const float*)d_in[7];
  const float* bo = (const float*)d_in[8];
  float* out = (float*)d_out;

  u16* ws      = (u16*)d_ws;
  u16* Wf_qkv  = ws;                            // [1536 chunks][64][8] 32x32 B-frag
  u16* Wf_o    = Wf_qkv + 3*HD_*D_;             // [512 chunks][64][8] 16x16 B-frag
  u16* Q       = Wf_o   + (size_t)D_*HD_;       // [B*L][128] row-major (pre-scaled)
  u16* Kf      = Q + (size_t)M_*HD_;            // [B][64][16][64][8] frag-major
  u16* Vf      = Kf + (size_t)M_*HD_;           // [B][64][16][64][8] frag-major
  u16* AOf     = Vf + (size_t)M_*HD_;           // [M/32][4][2][64][8] frag-major

  prepw_kernel<<<256, 256, 0, stream>>>(Wq, Wk, Wv, Wo, Wf_qkv, Wf_o);
  qkv_kernel<<<256, 512, 0, stream>>>(x, Wf_qkv, bq, bk, bv, Q, Kf, Vf);
  attn_kernel<<<512, 256, 0, stream>>>(Q, Kf, Vf, AOf);
  proj_kernel<<<dim3(8, 512), 256, 0, stream>>>(AOf, Wf_o, bo, out);
}

// Round 15
// 178.120 us; speedup vs baseline: 1.1701x; 1.1701x over previous
//
#include <hip/hip_runtime.h>

#define B_  4
#define L_  4096
#define D_  2048
#define HD_ 128
#define M_  (B_*L_)   // 16384

typedef __attribute__((ext_vector_type(8))) short short8;
typedef __attribute__((ext_vector_type(4))) float f32x4;
typedef __attribute__((ext_vector_type(16))) float f32x16;
typedef __attribute__((ext_vector_type(4))) unsigned short u16x4;
typedef __attribute__((ext_vector_type(4))) unsigned int u32x4;
typedef unsigned short u16;

#define GLL16(g, l) __builtin_amdgcn_global_load_lds( \
    (const __attribute__((address_space(1))) void*)(g), \
    (__attribute__((address_space(3))) void*)(l), 16, 0, 0)

__device__ __forceinline__ u16 f2bf(float f){
  union { float f; unsigned u; } v; v.f = f;
  unsigned r = v.u + 0x7FFFu + ((v.u >> 16) & 1u);
  return (u16)(r >> 16);
}

__device__ __forceinline__ unsigned cvtpk_bf16(float a, float b){
  unsigned r;
  asm volatile("v_cvt_pk_bf16_f32 %0, %1, %2" : "=v"(r) : "v"(a), "v"(b));
  return r;
}

// ---------------- prep: weights -> bf16 fragment-major layouts (R8) --------
// Wf_qkv chunks: chunk = (t*2+ks)*24 + g  (t = K>>6, ks = (K>>5)&1, g = col>>4)
//   element [lane][j]: lane = ((K>>3)&3)*16 + (col&15), j = K&7
// Wf_o chunks: chunk = (K>>5)*128 + (col>>4)
__global__ __launch_bounds__(256) void prep_kernel(
    const float* __restrict__ Wq, const float* __restrict__ Wk,
    const float* __restrict__ Wv, const float* __restrict__ Wo,
    u16* __restrict__ Wf_qkv, u16* __restrict__ Wf_o)
{
  __shared__ float T[64][68];
  const int tid = threadIdx.x;
  int tb = blockIdx.x;                 // 0..255
  int mat = tb >> 6, tt = tb & 63;
  const float* src; int Cw, rt, ct;
  if (mat < 3) {
    src = (mat==0) ? Wq : (mat==1) ? Wk : Wv;
    Cw = HD_; rt = tt >> 1; ct = tt & 1;
  } else {
    src = Wo;
    Cw = D_; rt = tt >> 5; ct = tt & 31;
  }
  int r0 = rt*64, c0 = ct*64;
  #pragma unroll
  for (int i=0;i<4;i++){
    int fid = i*256 + tid;
    int row = fid >> 4, c4 = (fid & 15) * 4;
    float4 v = *reinterpret_cast<const float4*>(src + (size_t)(r0+row)*Cw + c0 + c4);
    *reinterpret_cast<float4*>(&T[row][c4]) = v;
  }
  __syncthreads();
  #pragma unroll
  for (int i=0;i<2;i++){
    int sid = i*256 + tid;
    int crow = sid >> 3, k8 = (sid & 7) * 8;
    short8 o;
    #pragma unroll
    for (int j=0;j<8;j++) o[j] = (short)f2bf(T[k8+j][crow]);
    int K = r0 + k8;
    if (mat < 3) {
      int C = mat*128 + c0 + crow;           // global col 0..383
      int t2 = K >> 6, ks = (K >> 5) & 1, lh = (K >> 3) & 3;
      int g = C >> 4, l15c = C & 15;
      size_t off = ((size_t)((t2*2 + ks)*24 + g)*64 + (lh*16 + l15c))*8;
      *reinterpret_cast<short8*>(Wf_qkv + off) = o;
    } else {
      int C = c0 + crow;                     // global col 0..2047
      int ks = K >> 5, lh = (K >> 3) & 3;
      int g = C >> 4, l15c = C & 15;
      size_t off = ((size_t)(ks*128 + g)*64 + (lh*16 + l15c))*8;
      *reinterpret_cast<short8*>(Wf_o + off) = o;
    }
  }
}

// ---------------- fused QKV GEMM: R8 structure, BM=64 ----------------------
// grid 256 (BM=64, 2 blocks/CU), 256 thr = 4 col-waves (wave = 64 rows x 96).
// B frags: contiguous 1KB loads from Wf (L2-resident, no LDS).
// A: x fp32 staged HBM->LDS via GLL16 (XOR-swizzled source), cvt_pk in-reg.
// Q pre-scaled by 1/sqrt(HD); K/V written attn-fragment-major.
__global__ __launch_bounds__(256, 2) void qkv_kernel(
    const float* __restrict__ x, const u16* __restrict__ Wf,
    const float* __restrict__ bq, const float* __restrict__ bk,
    const float* __restrict__ bv,
    u16* __restrict__ Q, u16* __restrict__ Kf, u16* __restrict__ Vf)
{
  const int rb = blockIdx.x;          // 0..255
  const int tid  = threadIdx.x;
  const int lane = tid & 63, w = tid >> 6;
  const int l15 = lane & 15, lhi = lane >> 4;
  const int row0 = rb * 64;

  __shared__ float Asm[2][64*64];     // fp32 x tile, swizzled content, dbuf

  // GLL staging: 4 chunks per wave (chunk c covers rows 4c..4c+3)
  const float* aSrc[4];
  #pragma unroll
  for (int i=0;i<4;i++){
    int c = w*4 + i;
    int row = c*4 + (lane >> 4);            // lane>>4 in 0..3
    int k4  = (lane & 15) * 4;
    int ksrc = k4 ^ ((row & 7) << 3);       // pre-swizzled source (rule 21)
    aSrc[i] = x + (size_t)(row0 + row)*D_ + ksrc;
  }
  // A frag LDS offsets (floats), swizzle-matched: row = m*16+l15
  int offA[2][4];
  #pragma unroll
  for (int ks=0;ks<2;ks++)
    #pragma unroll
    for (int m=0;m<4;m++)
      offA[ks][m] = (m*16 + l15)*64 + ((ks*32 + lhi*8) ^ ((l15 & 7) << 3));

  const u16* wfLane = Wf + lane*8;

  f32x4 acc[4][6];
  f32x4 zero4 = {0.f,0.f,0.f,0.f};
  #pragma unroll
  for (int m=0;m<4;m++)
    #pragma unroll
    for (int n=0;n<6;n++) acc[m][n] = zero4;

  // prologue: stage tile 0
  #pragma unroll
  for (int i=0;i<4;i++){
    GLL16(aSrc[i], &Asm[0][(w*4+i)*256]);
    aSrc[i] += 64;
  }
  __syncthreads();

  for (int t = 0; t < 32; ++t) {
    const int cur = t & 1;
    if (t + 1 < 32) {
      #pragma unroll
      for (int i=0;i<4;i++){
        GLL16(aSrc[i], &Asm[cur^1][(w*4+i)*256]);
        aSrc[i] += 64;
      }
    }
    const float* Ac = &Asm[cur][0];
    #pragma unroll
    for (int ks=0;ks<2;ks++){
      // B frags: 6 contiguous 1KB loads (shared across all 4 m)
      short8 fb[6];
      const u16* fbp = wfLane + (size_t)((t*2 + ks)*24 + w*6)*512;
      #pragma unroll
      for (int n=0;n<6;n++)
        fb[n] = *reinterpret_cast<const short8*>(fbp + n*512);
      // A frags: LDS fp32 -> bf16
      short8 fa[4];
      #pragma unroll
      for (int m=0;m<4;m++){
        float4 f0 = *reinterpret_cast<const float4*>(Ac + offA[ks][m]);
        float4 f1 = *reinterpret_cast<const float4*>(Ac + offA[ks][m] + 4);
        union { u32x4 u; short8 s8; } tt;
        tt.u[0] = cvtpk_bf16(f0.x, f0.y);
        tt.u[1] = cvtpk_bf16(f0.z, f0.w);
        tt.u[2] = cvtpk_bf16(f1.x, f1.y);
        tt.u[3] = cvtpk_bf16(f1.z, f1.w);
        fa[m] = tt.s8;
      }
      __builtin_amdgcn_s_setprio(1);
      #pragma unroll
      for (int m=0;m<4;m++)
        #pragma unroll
        for (int n=0;n<6;n++)
          acc[m][n] = __builtin_amdgcn_mfma_f32_16x16x32_bf16(fa[m], fb[n], acc[m][n], 0, 0, 0);
      __builtin_amdgcn_s_setprio(0);
    }
    __syncthreads();
  }

  const float qscale = 0.08838834764831845f;  // 1/sqrt(128)
  #pragma unroll
  for (int n=0;n<6;n++){
    int col = w*96 + n*16 + l15;
    int j = col >> 7;            // 0:Q 1:K 2:V
    int c = col & 127;
    float bi = (j==0) ? bq[c] : (j==1) ? bk[c] : bv[c];
    #pragma unroll
    for (int m=0;m<4;m++){
      int rowb = row0 + m*16 + (lhi<<2);
      int bb = rowb >> 12;
      int l0 = rowb & (L_-1);
      if (j == 0) {
        #pragma unroll
        for (int r=0;r<4;r++)
          Q[(size_t)(rowb+r)*HD_ + c] = f2bf((acc[m][n][r] + bi) * qscale);
      } else if (j == 1) {
        int ksd = c >> 4, hid = (c >> 3) & 1, jd = c & 7;
        #pragma unroll
        for (int r=0;r<4;r++){
          int l = l0 + r;
          int kt = l >> 6, k6 = l & 63;
          int n2 = k6 >> 5, l31k = k6 & 31;
          Kf[((size_t)bb*64 + kt)*8192 + (n2*8 + ksd)*512 + (hid*32 + l31k)*8 + jd]
              = f2bf(acc[m][n][r] + bi);
        }
      } else {
        int nbv = (c >> 5) & 3, l31v = c & 31;
        int kt = l0 >> 6, k6 = l0 & 63;
        int ksv = k6 >> 4, hiv = (k6 >> 3) & 1, j0 = k6 & 7;
        u16x4 v4;
        #pragma unroll
        for (int r=0;r<4;r++) v4[r] = f2bf(acc[m][n][r] + bi);
        *reinterpret_cast<u16x4*>(
            Vf + ((size_t)bb*64 + kt)*8192 + (ksv*4 + nbv)*512 + (hiv*32 + l31v)*8 + j0) = v4;
      }
    }
  }
}

// ---------------- flash attention: 32x32 swapped-QK^T, frag-major K/V ------
__global__ __launch_bounds__(256, 2) void attn_kernel(
    const u16* __restrict__ Qg, const u16* __restrict__ Kfg,
    const u16* __restrict__ Vfg, u16* __restrict__ AOf)
{
  const int blk = blockIdx.x;
  const int xcd = blk & 7;
  const int sub = blk >> 3;                    // 0..63
  const int b   = xcd >> 1;                    // batch -> XCD pair
  const int strip = 127 - (2*sub + (xcd & 1)); // long strips dispatch first
  const int q0  = strip * 32;
  const int KT  = (strip >> 1) + 1;            // #64-key tiles

  const int tid = threadIdx.x, lane = tid & 63, w = tid >> 6;
  const int l31 = lane & 31;
  const int hi  = lane >> 5;

  const u16* Qb  = Qg  + (size_t)b * L_ * HD_;
  const u16* Kfb = Kfg + (size_t)b * 64 * 8192 + lane*8;
  const u16* Vfb = Vfg + (size_t)b * 64 * 8192 + lane*8;

  __shared__ __attribute__((aligned(16))) float Ol[4][32][132];
  __shared__ float Ml[4][32], Ll[4][32];

  short8 qf[8];
  #pragma unroll
  for (int ks=0; ks<8; ks++)
    qf[ks] = *reinterpret_cast<const short8*>(
        &Qb[(size_t)(q0 + l31)*HD_ + ks*16 + hi*8]);

  f32x16 O[4];
  #pragma unroll
  for (int nb=0; nb<4; nb++)
    #pragma unroll
    for (int i=0;i<16;i++) O[nb][i] = 0.f;
  float m_ = -__builtin_inff();
  float l_ = 0.f;

  for (int kt = w; kt < KT; kt += 4) {
    const u16* Kt = Kfb + (size_t)kt*8192;
    f32x16 s[2];
    #pragma unroll
    for (int n=0;n<2;n++)
      #pragma unroll
      for (int i=0;i<16;i++) s[n][i] = 0.f;
    __builtin_amdgcn_s_setprio(1);
    #pragma unroll
    for (int ks=0;ks<8;ks++)
      #pragma unroll
      for (int n=0;n<2;n++){
        short8 ka = *reinterpret_cast<const short8*>(Kt + (n*8 + ks)*512);
        s[n] = __builtin_amdgcn_mfma_f32_32x32x16_bf16(ka, qf[ks], s[n], 0, 0, 0);
      }
    __builtin_amdgcn_s_setprio(0);

    if (kt == KT-1) {
      #pragma unroll
      for (int n=0;n<2;n++)
        #pragma unroll
        for (int reg=0;reg<16;reg++){
          int key = kt*64 + n*32 + (reg&3) + 8*(reg>>2) + 4*hi;
          if (key > q0 + l31) s[n][reg] = -__builtin_inff();
        }
    }

    float pmax = s[0][0];
    #pragma unroll
    for (int n=0;n<2;n++)
      #pragma unroll
      for (int reg=0;reg<16;reg++) pmax = fmaxf(pmax, s[n][reg]);
    pmax = fmaxf(pmax, __shfl_xor(pmax, 32, 64));

    if (!__all(pmax <= m_ + 8.f)) {
      float mnew = fmaxf(m_, pmax);
      float alpha = __expf(m_ - mnew);
      m_ = mnew;
      l_ *= alpha;
      #pragma unroll
      for (int nb=0; nb<4; nb++)
        #pragma unroll
        for (int i=0;i<16;i++) O[nb][i] *= alpha;
    }

    float rsum = 0.f;
    #pragma unroll
    for (int n=0;n<2;n++)
      #pragma unroll
      for (int reg=0;reg<16;reg++){
        float p = __expf(s[n][reg] - m_);
        s[n][reg] = p;
        rsum += p;
      }
    rsum += __shfl_xor(rsum, 32, 64);
    l_ += rsum;

    unsigned c[2][8], ox[2][8];
    #pragma unroll
    for (int n=0;n<2;n++)
      #pragma unroll
      for (int i=0;i<8;i++)
        c[n][i] = cvtpk_bf16(s[n][2*i], s[n][2*i+1]);
    #pragma unroll
    for (int n=0;n<2;n++)
      #pragma unroll
      for (int i=0;i<8;i++)
        ox[n][i] = (unsigned)__shfl_xor((int)c[n][i], 32, 64);

    short8 pb[4];
    #pragma unroll
    for (int n=0;n<2;n++)
      #pragma unroll
      for (int sB=0;sB<2;sB++){
        union { u32x4 u; short8 s8; } t;
        t.u[0] = hi ? ox[n][4*sB+2] : c[n][4*sB+0];
        t.u[1] = hi ? ox[n][4*sB+3] : c[n][4*sB+1];
        t.u[2] = hi ? c[n][4*sB+2]  : ox[n][4*sB+0];
        t.u[3] = hi ? c[n][4*sB+3]  : ox[n][4*sB+1];
        pb[2*n+sB] = t.s8;
      }

    const u16* Vt2 = Vfb + (size_t)kt*8192;
    __builtin_amdgcn_s_setprio(1);
    #pragma unroll
    for (int ks=0; ks<4; ks++){
      #pragma unroll
      for (int nb=0; nb<4; nb++){
        short8 av = *reinterpret_cast<const short8*>(Vt2 + (ks*4 + nb)*512);
        O[nb] = __builtin_amdgcn_mfma_f32_32x32x16_bf16(av, pb[ks], O[nb], 0, 0, 0);
      }
    }
    __builtin_amdgcn_s_setprio(0);
  }

  if (hi == 0) { Ml[w][l31] = m_; Ll[w][l31] = l_; }
  #pragma unroll
  for (int nb=0; nb<4; nb++)
    #pragma unroll
    for (int g=0; g<4; g++){
      f32x4 v;
      v[0]=O[nb][4*g+0]; v[1]=O[nb][4*g+1]; v[2]=O[nb][4*g+2]; v[3]=O[nb][4*g+3];
      *reinterpret_cast<f32x4*>(&Ol[w][l31][nb*32 + g*8 + hi*4]) = v;
    }
  __syncthreads();

  {
    int q  = tid >> 3;
    int dc = (tid & 7) * 16;
    float mw[4], lw[4];
    float M = -__builtin_inff();
    #pragma unroll
    for (int w2=0; w2<4; w2++){ mw[w2]=Ml[w2][q]; lw[w2]=Ll[w2][q]; M = fmaxf(M, mw[w2]); }
    float den = 0.f, cw[4];
    #pragma unroll
    for (int w2=0; w2<4; w2++){ float e = __expf(mw[w2]-M); cw[w2]=e; den += lw[w2]*e; }
    float inv = 1.0f/den;
    float o[16];
    #pragma unroll
    for (int j=0;j<16;j++) o[j] = 0.f;
    #pragma unroll
    for (int w2=0; w2<4; w2++){
      #pragma unroll
      for (int g=0; g<4; g++){
        f32x4 p = *reinterpret_cast<const f32x4*>(&Ol[w2][q][dc + g*4]);
        #pragma unroll
        for (int j=0;j<4;j++) o[g*4+j] += cw[w2]*p[j];
      }
    }
    short8 st0, st1;
    #pragma unroll
    for (int j=0;j<8;j++){ st0[j] = (short)f2bf(o[j]*inv); st1[j] = (short)f2bf(o[8+j]*inv); }
    size_t rowg = (size_t)b*L_ + q0 + q;
    size_t rb2g = rowg >> 5;
    int qq = (int)(rowg & 31);
    int mA = qq >> 4, l15A = qq & 15;
    int ks0 = dc >> 5,      lh0 = (dc >> 3) & 3;
    int ks1 = (dc+8) >> 5,  lh1 = ((dc+8) >> 3) & 3;
    *reinterpret_cast<short8*>(AOf + ((rb2g*4 + ks0)*2 + mA)*512 + (lh0*16 + l15A)*8) = st0;
    *reinterpret_cast<short8*>(AOf + ((rb2g*4 + ks1)*2 + mA)*512 + (lh1*16 + l15A)*8) = st1;
  }
}

// ---------------- output projection: frag-major, LDS-free, single pass -----
__global__ __launch_bounds__(256) void proj_kernel(
    const u16* __restrict__ AOf, const u16* __restrict__ Wf_o,
    const float* __restrict__ bo, float* __restrict__ out)
{
  const int nb  = blockIdx.x;   // 0..7
  const int rbk = blockIdx.y;   // 0..511
  const int tid = threadIdx.x, lane = tid & 63, w = tid >> 6;
  const int l15 = lane & 15, lhi = lane >> 4;

  const u16* faBase = AOf  + (size_t)rbk*8*512 + lane*8;
  const u16* fbBase = Wf_o + lane*8;

  f32x4 acc[2][4];
  f32x4 zero4 = {0.f,0.f,0.f,0.f};
  #pragma unroll
  for (int m=0;m<2;m++)
    #pragma unroll
    for (int n=0;n<4;n++) acc[m][n] = zero4;

  #pragma unroll
  for (int ks=0; ks<4; ks++){
    short8 fa[2], fb[4];
    #pragma unroll
    for (int m=0;m<2;m++)
      fa[m] = *reinterpret_cast<const short8*>(faBase + (ks*2 + m)*512);
    #pragma unroll
    for (int n=0;n<4;n++)
      fb[n] = *reinterpret_cast<const short8*>(
          fbBase + (size_t)(ks*128 + nb*16 + w*4 + n)*512);
    #pragma unroll
    for (int m=0;m<2;m++)
      #pragma unroll
      for (int n=0;n<4;n++)
        acc[m][n] = __builtin_amdgcn_mfma_f32_16x16x32_bf16(fa[m], fb[n], acc[m][n], 0, 0, 0);
  }

  #pragma unroll
  for (int n=0;n<4;n++){
    int col = nb*256 + w*64 + n*16 + l15;
    float bi = bo[col];
    #pragma unroll
    for (int m=0;m<2;m++){
      int row = rbk*32 + m*16 + (lhi<<2);
      #pragma unroll
      for (int r=0;r<4;r++)
        out[(size_t)(row+r)*D_ + col] = acc[m][n][r] + bi;
    }
  }
}

// ---------------- launch ----------------
extern "C" void kernel_launch(void* const* d_in, const int* in_sizes, int n_in,
                              void* d_out, int out_size, void* d_ws, size_t ws_size,
                              hipStream_t stream) {
  const float* x  = (const float*)d_in[0];
  const float* Wq = (const float*)d_in[1];
  const float* bq = (const float*)d_in[2];
  const float* Wk = (const float*)d_in[3];
  const float* bk = (const float*)d_in[4];
  const float* Wv = (const float*)d_in[5];
  const float* bv = (const float*)d_in[6];
  const float* Wo = (const float*)d_in[7];
  const float* bo = (const float*)d_in[8];
  float* out = (float*)d_out;

  u16* ws      = (u16*)d_ws;
  u16* Wf_qkv  = ws;                            // [1536 chunks][64][8] 16x16 B-frag
  u16* Wf_o    = Wf_qkv + 3*HD_*D_;             // [512 chunks][64][8] 16x16 B-frag
  u16* Q       = Wf_o   + (size_t)D_*HD_;       // [B*L][128] row-major (pre-scaled)
  u16* Kf      = Q + (size_t)M_*HD_;            // [B][64][2][8][64][8] frag-major
  u16* Vf      = Kf + (size_t)M_*HD_;           // [B][64][4][4][64][8] frag-major
  u16* AOf     = Vf + (size_t)M_*HD_;           // [M/32][4][2][64][8] frag-major

  prep_kernel<<<256, 256, 0, stream>>>(Wq, Wk, Wv, Wo, Wf_qkv, Wf_o);
  qkv_kernel<<<256, 256, 0, stream>>>(x, Wf_qkv, bq, bk, bv, Q, Kf, Vf);
  attn_kernel<<<512, 256, 0, stream>>>(Q, Kf, Vf, AOf);
  proj_kernel<<<dim3(8, 512), 256, 0, stream>>>(AOf, Wf_o, bo, out);
}

// Round 16
// 173.895 us; speedup vs baseline: 1.1985x; 1.0243x over previous
//
#include <hip/hip_runtime.h>

#define B_  4
#define L_  4096
#define D_  2048
#define HD_ 128
#define M_  (B_*L_)   // 16384

typedef __attribute__((ext_vector_type(8))) short short8;
typedef __attribute__((ext_vector_type(4))) float f32x4;
typedef __attribute__((ext_vector_type(16))) float f32x16;
typedef __attribute__((ext_vector_type(4))) unsigned short u16x4;
typedef __attribute__((ext_vector_type(4))) unsigned int u32x4;
typedef unsigned short u16;

#define GLL16(g, l) __builtin_amdgcn_global_load_lds( \
    (const __attribute__((address_space(1))) void*)(g), \
    (__attribute__((address_space(3))) void*)(l), 16, 0, 0)

__device__ __forceinline__ u16 f2bf(float f){
  union { float f; unsigned u; } v; v.f = f;
  unsigned r = v.u + 0x7FFFu + ((v.u >> 16) & 1u);
  return (u16)(r >> 16);
}

__device__ __forceinline__ unsigned cvtpk_bf16(float a, float b){
  unsigned r;
  asm volatile("v_cvt_pk_bf16_f32 %0, %1, %2" : "=v"(r) : "v"(a), "v"(b));
  return r;
}

// ---------------- prep: weights -> bf16 fragment-major layouts -------------
// Wf_qkv chunks: chunk = (t*2+ks)*24 + g  (t = K>>6, ks = (K>>5)&1, g = col>>4)
//   element [lane][j]: lane = ((K>>3)&3)*16 + (col&15), j = K&7
// Wf_o chunks: chunk = ks*128 + (col>>4), ks = K>>5 (K in 0..127 = HD dim)
__global__ __launch_bounds__(256) void prep_kernel(
    const float* __restrict__ Wq, const float* __restrict__ Wk,
    const float* __restrict__ Wv, const float* __restrict__ Wo,
    u16* __restrict__ Wf_qkv, u16* __restrict__ Wf_o)
{
  __shared__ float T[64][68];
  const int tid = threadIdx.x;
  int tb = blockIdx.x;                 // 0..255
  int mat = tb >> 6, tt = tb & 63;
  const float* src; int Rw, Cw, rt, ct;
  if (mat < 3) {
    src = (mat==0) ? Wq : (mat==1) ? Wk : Wv;
    Rw = D_; Cw = HD_; rt = tt >> 1; ct = tt & 1;
  } else {
    src = Wo;
    Rw = HD_; Cw = D_; rt = tt >> 5; ct = tt & 31;
  }
  int r0 = rt*64, c0 = ct*64;
  #pragma unroll
  for (int i=0;i<4;i++){
    int fid = i*256 + tid;
    int row = fid >> 4, c4 = (fid & 15) * 4;
    float4 v = *reinterpret_cast<const float4*>(src + (size_t)(r0+row)*Cw + c0 + c4);
    *reinterpret_cast<float4*>(&T[row][c4]) = v;
  }
  __syncthreads();
  #pragma unroll
  for (int i=0;i<2;i++){
    int sid = i*256 + tid;
    int crow = sid >> 3, k8 = (sid & 7) * 8;
    short8 o;
    #pragma unroll
    for (int j=0;j<8;j++) o[j] = (short)f2bf(T[k8+j][crow]);
    int K = r0 + k8;
    if (mat < 3) {
      int C = mat*128 + c0 + crow;           // global col 0..383
      int t2 = K >> 6, ks = (K >> 5) & 1, lh = (K >> 3) & 3;
      int g = C >> 4, l15c = C & 15;
      size_t off = ((size_t)((t2*2 + ks)*24 + g)*64 + (lh*16 + l15c))*8;
      *reinterpret_cast<short8*>(Wf_qkv + off) = o;
    } else {
      int C = c0 + crow;                     // global col 0..2047
      int ks = K >> 5, lh = (K >> 3) & 3;
      int g = C >> 4, l15c = C & 15;
      size_t off = ((size_t)(ks*128 + g)*64 + (lh*16 + l15c))*8;
      *reinterpret_cast<short8*>(Wf_o + off) = o;
    }
  }
}

// ---------------- fused QKV GEMM: frag-major B from L2, A via GLL16 --------
// grid 512 (2 blocks/CU), 256 thr = 4 waves (wc = w), tile 32 rows x 384 cols.
// B frags: contiguous 1KB loads from Wf (L2-resident, no LDS).
// A: x fp32 staged HBM->LDS via GLL16 (swizzled source), cvt_pk in-reg.
// Q pre-scaled by 1/sqrt(HD); K/V written attn-fragment-major.
__global__ __launch_bounds__(256, 2) void qkv_kernel(
    const float* __restrict__ x, const u16* __restrict__ Wf,
    const float* __restrict__ bq, const float* __restrict__ bk,
    const float* __restrict__ bv,
    u16* __restrict__ Q, u16* __restrict__ Kf, u16* __restrict__ Vf)
{
  const int rb = blockIdx.x;          // 0..511
  const int tid  = threadIdx.x;
  const int lane = tid & 63, w = tid >> 6;
  const int l15 = lane & 15, lhi = lane >> 4;
  const int row0 = rb * 32;

  __shared__ float Asm[2][32*64];     // fp32 x tile, swizzled content, dbuf

  // GLL staging: 2 chunks per wave (chunk c covers rows 4c..4c+3)
  const float* aSrc[2]; 
  #pragma unroll
  for (int i=0;i<2;i++){
    int c = w*2 + i;
    int row = c*4 + (lane >> 4);            // lane>>4 in 0..3
    int k4  = (lane & 15) * 4;
    int ksrc = k4 ^ ((row & 7) << 3);       // pre-swizzled source (rule 21)
    aSrc[i] = x + (size_t)(row0 + row)*D_ + ksrc;
  }
  // A frag LDS offsets (floats), swizzle-matched: row = m*16+l15
  int offA[2][2];
  #pragma unroll
  for (int ks=0;ks<2;ks++)
    #pragma unroll
    for (int m=0;m<2;m++)
      offA[ks][m] = (m*16 + l15)*64 + ((ks*32 + lhi*8) ^ ((l15 & 7) << 3));

  const u16* wfLane = Wf + lane*8;

  f32x4 acc[2][6];
  f32x4 zero4 = {0.f,0.f,0.f,0.f};
  #pragma unroll
  for (int m=0;m<2;m++)
    #pragma unroll
    for (int n=0;n<6;n++) acc[m][n] = zero4;

  // prologue: stage tile 0
  #pragma unroll
  for (int i=0;i<2;i++){
    GLL16(aSrc[i], &Asm[0][(w*2+i)*256]);
    aSrc[i] += 64;
  }
  __syncthreads();

  for (int t = 0; t < 32; ++t) {
    const int cur = t & 1;
    if (t + 1 < 32) {
      #pragma unroll
      for (int i=0;i<2;i++){
        GLL16(aSrc[i], &Asm[cur^1][(w*2+i)*256]);
        aSrc[i] += 64;
      }
    }
    const float* Ac = &Asm[cur][0];
    #pragma unroll
    for (int ks=0;ks<2;ks++){
      // B frags: 6 contiguous 1KB loads
      short8 fb[6];
      const u16* fbp = wfLane + (size_t)((t*2 + ks)*24 + w*6)*512;
      #pragma unroll
      for (int n=0;n<6;n++)
        fb[n] = *reinterpret_cast<const short8*>(fbp + n*512);
      // A frags: LDS fp32 -> bf16
      short8 fa[2];
      #pragma unroll
      for (int m=0;m<2;m++){
        float4 f0 = *reinterpret_cast<const float4*>(Ac + offA[ks][m]);
        float4 f1 = *reinterpret_cast<const float4*>(Ac + offA[ks][m] + 4);
        union { u32x4 u; short8 s8; } tt;
        tt.u[0] = cvtpk_bf16(f0.x, f0.y);
        tt.u[1] = cvtpk_bf16(f0.z, f0.w);
        tt.u[2] = cvtpk_bf16(f1.x, f1.y);
        tt.u[3] = cvtpk_bf16(f1.z, f1.w);
        fa[m] = tt.s8;
      }
      #pragma unroll
      for (int m=0;m<2;m++)
        #pragma unroll
        for (int n=0;n<6;n++)
          acc[m][n] = __builtin_amdgcn_mfma_f32_16x16x32_bf16(fa[m], fb[n], acc[m][n], 0, 0, 0);
    }
    __syncthreads();
  }

  const float qscale = 0.08838834764831845f;  // 1/sqrt(128)
  #pragma unroll
  for (int n=0;n<6;n++){
    int col = w*96 + n*16 + l15;
    int j = col >> 7;            // 0:Q 1:K 2:V
    int c = col & 127;
    float bi = (j==0) ? bq[c] : (j==1) ? bk[c] : bv[c];
    #pragma unroll
    for (int m=0;m<2;m++){
      int rowb = row0 + m*16 + (lhi<<2);
      int bb = rowb >> 12;
      int l0 = rowb & (L_-1);
      if (j == 0) {
        #pragma unroll
        for (int r=0;r<4;r++)
          Q[(size_t)(rowb+r)*HD_ + c] = f2bf((acc[m][n][r] + bi) * qscale);
      } else if (j == 1) {
        int ksd = c >> 4, hid = (c >> 3) & 1, jd = c & 7;
        #pragma unroll
        for (int r=0;r<4;r++){
          int l = l0 + r;
          int kt = l >> 6, k6 = l & 63;
          int n2 = k6 >> 5, l31k = k6 & 31;
          Kf[((size_t)bb*64 + kt)*8192 + (n2*8 + ksd)*512 + (hid*32 + l31k)*8 + jd]
              = f2bf(acc[m][n][r] + bi);
        }
      } else {
        int nbv = (c >> 5) & 3, l31v = c & 31;
        int kt = l0 >> 6, k6 = l0 & 63;
        int ksv = k6 >> 4, hiv = (k6 >> 3) & 1, j0 = k6 & 7;
        u16x4 v4;
        #pragma unroll
        for (int r=0;r<4;r++) v4[r] = f2bf(acc[m][n][r] + bi);
        *reinterpret_cast<u16x4*>(
            Vf + ((size_t)bb*64 + kt)*8192 + (ksv*4 + nbv)*512 + (hiv*32 + l31v)*8 + j0) = v4;
      }
    }
  }
}

// ---------------- flash attention: 32x32 swapped-QK^T, frag-major K/V ------
// grid 512 (2/CU): block = 32 q-rows; 4 waves key-split (kt = w mod 4).
// Output written fragment-major (AOf) for proj's A-operand.
__global__ __launch_bounds__(256, 2) void attn_kernel(
    const u16* __restrict__ Qg, const u16* __restrict__ Kfg,
    const u16* __restrict__ Vfg, u16* __restrict__ AOf)
{
  const int blk = blockIdx.x;
  const int xcd = blk & 7;
  const int sub = blk >> 3;                    // 0..63
  const int b   = xcd >> 1;                    // batch -> XCD pair
  const int strip = 127 - (2*sub + (xcd & 1)); // long strips dispatch first
  const int q0  = strip * 32;
  const int KT  = (strip >> 1) + 1;            // #64-key tiles

  const int tid = threadIdx.x, lane = tid & 63, w = tid >> 6;
  const int l31 = lane & 31;
  const int hi  = lane >> 5;

  const u16* Qb  = Qg  + (size_t)b * L_ * HD_;
  const u16* Kfb = Kfg + (size_t)b * 64 * 8192 + lane*8;
  const u16* Vfb = Vfg + (size_t)b * 64 * 8192 + lane*8;

  __shared__ __attribute__((aligned(16))) float Ol[4][32][132];
  __shared__ float Ml[4][32], Ll[4][32];

  // Q B-frags (Q pre-scaled)
  short8 qf[8];
  #pragma unroll
  for (int ks=0; ks<8; ks++)
    qf[ks] = *reinterpret_cast<const short8*>(
        &Qb[(size_t)(q0 + l31)*HD_ + ks*16 + hi*8]);

  f32x16 O[4];
  #pragma unroll
  for (int nb=0; nb<4; nb++)
    #pragma unroll
    for (int i=0;i<16;i++) O[nb][i] = 0.f;
  float m_ = -__builtin_inff();
  float l_ = 0.f;

  for (int kt = w; kt < KT; kt += 4) {
    const u16* Kt = Kfb + (size_t)kt*8192;
    f32x16 s[2];
    #pragma unroll
    for (int n=0;n<2;n++)
      #pragma unroll
      for (int i=0;i<16;i++) s[n][i] = 0.f;
    __builtin_amdgcn_s_setprio(1);
    #pragma unroll
    for (int ks=0;ks<8;ks++)
      #pragma unroll
      for (int n=0;n<2;n++){
        short8 ka = *reinterpret_cast<const short8*>(Kt + (n*8 + ks)*512);
        s[n] = __builtin_amdgcn_mfma_f32_32x32x16_bf16(ka, qf[ks], s[n], 0, 0, 0);
      }
    __builtin_amdgcn_s_setprio(0);

    if (kt == KT-1) {
      #pragma unroll
      for (int n=0;n<2;n++)
        #pragma unroll
        for (int reg=0;reg<16;reg++){
          int key = kt*64 + n*32 + (reg&3) + 8*(reg>>2) + 4*hi;
          if (key > q0 + l31) s[n][reg] = -__builtin_inff();
        }
    }

    float pmax = s[0][0];
    #pragma unroll
    for (int n=0;n<2;n++)
      #pragma unroll
      for (int reg=0;reg<16;reg++) pmax = fmaxf(pmax, s[n][reg]);
    pmax = fmaxf(pmax, __shfl_xor(pmax, 32, 64));

    if (!__all(pmax <= m_ + 8.f)) {
      float mnew = fmaxf(m_, pmax);
      float alpha = __expf(m_ - mnew);
      m_ = mnew;
      l_ *= alpha;
      #pragma unroll
      for (int nb=0; nb<4; nb++)
        #pragma unroll
        for (int i=0;i<16;i++) O[nb][i] *= alpha;
    }

    float rsum = 0.f;
    #pragma unroll
    for (int n=0;n<2;n++)
      #pragma unroll
      for (int reg=0;reg<16;reg++){
        float p = __expf(s[n][reg] - m_);
        s[n][reg] = p;
        rsum += p;
      }
    rsum += __shfl_xor(rsum, 32, 64);
    l_ += rsum;

    unsigned c[2][8], ox[2][8];
    #pragma unroll
    for (int n=0;n<2;n++)
      #pragma unroll
      for (int i=0;i<8;i++)
        c[n][i] = cvtpk_bf16(s[n][2*i], s[n][2*i+1]);
    #pragma unroll
    for (int n=0;n<2;n++)
      #pragma unroll
      for (int i=0;i<8;i++)
        ox[n][i] = (unsigned)__shfl_xor((int)c[n][i], 32, 64);

    short8 pb[4];
    #pragma unroll
    for (int n=0;n<2;n++)
      #pragma unroll
      for (int sB=0;sB<2;sB++){
        union { u32x4 u; short8 s8; } t;
        t.u[0] = hi ? ox[n][4*sB+2] : c[n][4*sB+0];
        t.u[1] = hi ? ox[n][4*sB+3] : c[n][4*sB+1];
        t.u[2] = hi ? c[n][4*sB+2]  : ox[n][4*sB+0];
        t.u[3] = hi ? c[n][4*sB+3]  : ox[n][4*sB+1];
        pb[2*n+sB] = t.s8;
      }

    const u16* Vt2 = Vfb + (size_t)kt*8192;
    __builtin_amdgcn_s_setprio(1);
    #pragma unroll
    for (int ks=0; ks<4; ks++){
      #pragma unroll
      for (int nb=0; nb<4; nb++){
        short8 av = *reinterpret_cast<const short8*>(Vt2 + (ks*4 + nb)*512);
        O[nb] = __builtin_amdgcn_mfma_f32_32x32x16_bf16(av, pb[ks], O[nb], 0, 0, 0);
      }
    }
    __builtin_amdgcn_s_setprio(0);
  }

  // publish partials
  if (hi == 0) { Ml[w][l31] = m_; Ll[w][l31] = l_; }
  #pragma unroll
  for (int nb=0; nb<4; nb++)
    #pragma unroll
    for (int g=0; g<4; g++){
      f32x4 v;
      v[0]=O[nb][4*g+0]; v[1]=O[nb][4*g+1]; v[2]=O[nb][4*g+2]; v[3]=O[nb][4*g+3];
      *reinterpret_cast<f32x4*>(&Ol[w][l31][nb*32 + g*8 + hi*4]) = v;
    }
  __syncthreads();

  // merge 4 key-split partials; write AOf fragment-major
  {
    int q  = tid >> 3;
    int dc = (tid & 7) * 16;
    float mw[4], lw[4];
    float M = -__builtin_inff();
    #pragma unroll
    for (int w2=0; w2<4; w2++){ mw[w2]=Ml[w2][q]; lw[w2]=Ll[w2][q]; M = fmaxf(M, mw[w2]); }
    float den = 0.f, cw[4];
    #pragma unroll
    for (int w2=0; w2<4; w2++){ float e = __expf(mw[w2]-M); cw[w2]=e; den += lw[w2]*e; }
    float inv = 1.0f/den;
    float o[16];
    #pragma unroll
    for (int j=0;j<16;j++) o[j] = 0.f;
    #pragma unroll
    for (int w2=0; w2<4; w2++){
      #pragma unroll
      for (int g=0; g<4; g++){
        f32x4 p = *reinterpret_cast<const f32x4*>(&Ol[w2][q][dc + g*4]);
        #pragma unroll
        for (int j=0;j<4;j++) o[g*4+j] += cw[w2]*p[j];
      }
    }
    short8 st0, st1;
    #pragma unroll
    for (int j=0;j<8;j++){ st0[j] = (short)f2bf(o[j]*inv); st1[j] = (short)f2bf(o[8+j]*inv); }
    size_t rowg = (size_t)b*L_ + q0 + q;
    size_t rb2g = rowg >> 5;
    int qq = (int)(rowg & 31);
    int mA = qq >> 4, l15A = qq & 15;
    int ks0 = dc >> 5,      lh0 = (dc >> 3) & 3;
    int ks1 = (dc+8) >> 5,  lh1 = ((dc+8) >> 3) & 3;
    *reinterpret_cast<short8*>(AOf + ((rb2g*4 + ks0)*2 + mA)*512 + (lh0*16 + l15A)*8) = st0;
    *reinterpret_cast<short8*>(AOf + ((rb2g*4 + ks1)*2 + mA)*512 + (lh1*16 + l15A)*8) = st1;
  }
}

// ---------------- output projection: frag-major, LDS-free, single pass -----
// grid (8, 512): nb = 256-col slab, rbk = 32-row slab. 4 waves x (32x64).
__global__ __launch_bounds__(256) void proj_kernel(
    const u16* __restrict__ AOf, const u16* __restrict__ Wf_o,
    const float* __restrict__ bo, float* __restrict__ out)
{
  const int nb  = blockIdx.x;   // 0..7
  const int rbk = blockIdx.y;   // 0..511
  const int tid = threadIdx.x, lane = tid & 63, w = tid >> 6;
  const int l15 = lane & 15, lhi = lane >> 4;

  const u16* faBase = AOf  + (size_t)rbk*8*512 + lane*8;
  const u16* fbBase = Wf_o + lane*8;

  f32x4 acc[2][4];
  f32x4 zero4 = {0.f,0.f,0.f,0.f};
  #pragma unroll
  for (int m=0;m<2;m++)
    #pragma unroll
    for (int n=0;n<4;n++) acc[m][n] = zero4;

  #pragma unroll
  for (int ks=0; ks<4; ks++){
    short8 fa[2], fb[4];
    #pragma unroll
    for (int m=0;m<2;m++)
      fa[m] = *reinterpret_cast<const short8*>(faBase + (ks*2 + m)*512);
    #pragma unroll
    for (int n=0;n<4;n++)
      fb[n] = *reinterpret_cast<const short8*>(
          fbBase + (size_t)(ks*128 + nb*16 + w*4 + n)*512);
    #pragma unroll
    for (int m=0;m<2;m++)
      #pragma unroll
      for (int n=0;n<4;n++)
        acc[m][n] = __builtin_amdgcn_mfma_f32_16x16x32_bf16(fa[m], fb[n], acc[m][n], 0, 0, 0);
  }

  #pragma unroll
  for (int n=0;n<4;n++){
    int col = nb*256 + w*64 + n*16 + l15;
    float bi = bo[col];
    #pragma unroll
    for (int m=0;m<2;m++){
      int row = rbk*32 + m*16 + (lhi<<2);
      #pragma unroll
      for (int r=0;r<4;r++)
        out[(size_t)(row+r)*D_ + col] = acc[m][n][r] + bi;
    }
  }
}

// ---------------- launch ----------------
extern "C" void kernel_launch(void* const* d_in, const int* in_sizes, int n_in,
                              void* d_out, int out_size, void* d_ws, size_t ws_size,
                              hipStream_t stream) {
  const float* x  = (const float*)d_in[0];
  const float* Wq = (const float*)d_in[1];
  const float* bq = (const float*)d_in[2];
  const float* Wk = (const float*)d_in[3];
  const float* bk = (const float*)d_in[4];
  const float* Wv = (const float*)d_in[5];
  const float* bv = (const float*)d_in[6];
  const float* Wo = (const float*)d_in[7];
  const float* bo = (const float*)d_in[8];
  float* out = (float*)d_out;

  u16* ws      = (u16*)d_ws;
  u16* Wf_qkv  = ws;                            // [1536 chunks][64][8] frag-major
  u16* Wf_o    = Wf_qkv + 3*HD_*D_;             // [512 chunks][64][8] frag-major
  u16* Q       = Wf_o   + (size_t)D_*HD_;       // [B*L][128] row-major (pre-scaled)
  u16* Kf      = Q + (size_t)M_*HD_;            // [B][64][2][8][64][8] frag-major
  u16* Vf      = Kf + (size_t)M_*HD_;           // [B][64][4][4][64][8] frag-major
  u16* AOf     = Vf + (size_t)M_*HD_;           // [M/32][4][2][64][8] frag-major

  prep_kernel<<<256, 256, 0, stream>>>(Wq, Wk, Wv, Wo, Wf_qkv, Wf_o);
  qkv_kernel<<<512, 256, 0, stream>>>(x, Wf_qkv, bq, bk, bv, Q, Kf, Vf);
  attn_kernel<<<512, 256, 0, stream>>>(Q, Kf, Vf, AOf);
  proj_kernel<<<dim3(8, 512), 256, 0, stream>>>(AOf, Wf_o, bo, out);
}